// Round 1
// baseline (197.406 us; speedup 1.0000x reference)
//
#include <hip/hip_runtime.h>

#define B_ 128
#define T_ 512
#define H_ 1024
#define K_ 7
#define START_ 5
#define STOP_ 6
#define NEG_ -10000.0f

// ---------------- Kernel 0: zero the scalar output ----------------
__global__ void zero_out_kernel(float* out) { out[0] = 0.0f; }

// ---------------- Kernel 1: emissions ----------------
// feats[b,t,k] = dot(features[b,t,:], W[k,:]) + bias[k],  stored [BT][8] (k<7 used)
// One wave per row; W staged in LDS (28 KB); float4 coalesced loads.
__global__ __launch_bounds__(256) void emis_kernel(
    const float* __restrict__ features, const float* __restrict__ W,
    const float* __restrict__ bias, float* __restrict__ feats) {
  __shared__ float Wlds[K_ * H_];
  const int tid = threadIdx.x;
  for (int idx = tid; idx < K_ * H_; idx += 256) Wlds[idx] = W[idx];
  __syncthreads();

  const int wave = tid >> 6;
  const int lane = tid & 63;
  const int row = blockIdx.x * 4 + wave;  // (b*T + t)

  const float4* f4p = (const float4*)(features + (size_t)row * H_);
  float acc[K_];
#pragma unroll
  for (int k = 0; k < K_; ++k) acc[k] = 0.0f;

#pragma unroll
  for (int c = 0; c < 4; ++c) {
    const float4 f = f4p[c * 64 + lane];  // features[row][c*256 + lane*4 ..+3]
#pragma unroll
    for (int k = 0; k < K_; ++k) {
      const float4 w = *(const float4*)(&Wlds[k * H_ + c * 256 + lane * 4]);
      acc[k] += f.x * w.x + f.y * w.y + f.z * w.z + f.w * w.w;
    }
  }

  // full-wave reduction of the 7 accumulators
#pragma unroll
  for (int k = 0; k < K_; ++k) {
    float v = acc[k];
#pragma unroll
    for (int off = 32; off > 0; off >>= 1) v += __shfl_xor(v, off, 64);
    acc[k] = v;
  }

  if (lane == 0) {
    float* o = feats + (size_t)row * 8;
#pragma unroll
    for (int k = 0; k < K_; ++k) o[k] = acc[k] + bias[k];
  }
}

// ---------------- Kernel 2: forward algorithm (partition function) ----------------
// 8 lanes per batch (lane-in-group = "next" tag, 7 active). Each lane keeps the
// whole fv[7] replicated in registers; per step it computes logsumexp over prev
// for its own next, then fv is redistributed with 7 intra-wave shuffles.
__global__ __launch_bounds__(64) void forward_kernel(
    const float* __restrict__ feats, const int* __restrict__ lengths,
    const float* __restrict__ transitions, float* __restrict__ out) {
  const int lane = threadIdx.x & 63;
  const int grp = lane >> 3;   // 8 groups per wave
  const int nx = lane & 7;     // next-tag index; active if < 7
  const int nxc = (nx < K_) ? nx : 0;
  const int batch = blockIdx.x * 8 + grp;
  const int base = grp * 8;

  float tr[K_];
#pragma unroll
  for (int p = 0; p < K_; ++p) tr[p] = transitions[nxc * K_ + p];

  float fv[K_];
#pragma unroll
  for (int p = 0; p < K_; ++p) fv[p] = (p == START_) ? 0.0f : NEG_;

  const int len = lengths[batch];
  int ml = len;
#pragma unroll
  for (int off = 32; off > 0; off >>= 1) ml = max(ml, __shfl_xor(ml, off, 64));

  const float* ep = feats + (size_t)batch * T_ * 8;

  for (int t = 0; t < ml; ++t) {
    const float emit = ep[t * 8 + nxc];
    float m = tr[0] + fv[0];
#pragma unroll
    for (int p = 1; p < K_; ++p) m = fmaxf(m, tr[p] + fv[p]);
    float s = 0.0f;
#pragma unroll
    for (int p = 0; p < K_; ++p) s += __expf(tr[p] + fv[p] - m);
    const float newv = emit + m + __logf(s);
    const float own = fv[nxc];
    const float val = (t < len) ? newv : own;  // freeze past sentence end
#pragma unroll
    for (int p = 0; p < K_; ++p) fv[p] = __shfl(val, base + p, 64);
  }

  // terminal: logsumexp(fv + transitions[STOP,:])
  if (nx == 0) {
    float tt[K_];
#pragma unroll
    for (int p = 0; p < K_; ++p) tt[p] = fv[p] + transitions[STOP_ * K_ + p];
    float m = tt[0];
#pragma unroll
    for (int p = 1; p < K_; ++p) m = fmaxf(m, tt[p]);
    float s = 0.0f;
#pragma unroll
    for (int p = 0; p < K_; ++p) s += __expf(tt[p] - m);
    atomicAdd(out, m + __logf(s));
  }
}

// ---------------- Kernel 3: gold score (subtracted) ----------------
__global__ __launch_bounds__(64) void gold_kernel(
    const float* __restrict__ feats, const int* __restrict__ tags,
    const int* __restrict__ lengths, const float* __restrict__ transitions,
    float* __restrict__ out) {
  const int b = blockIdx.x;
  const int lane = threadIdx.x;
  const int len = lengths[b];
  const int* tg = tags + (size_t)b * T_;
  const float* ep = feats + (size_t)b * T_ * 8;

  float partial = 0.0f;
  for (int t = lane; t < len; t += 64) {
    const int tag = tg[t];
    partial += ep[t * 8 + tag];                       // emission at gold tag
    const int prev = (t == 0) ? START_ : tg[t - 1];   // transition prev->tag
    partial += transitions[tag * K_ + prev];
  }
#pragma unroll
  for (int off = 32; off > 0; off >>= 1) partial += __shfl_xor(partial, off, 64);

  if (lane == 0) {
    partial += transitions[STOP_ * K_ + tg[len - 1]];  // tags[len-1] -> STOP
    atomicAdd(out, -partial);
  }
}

extern "C" void kernel_launch(void* const* d_in, const int* in_sizes, int n_in,
                              void* d_out, int out_size, void* d_ws, size_t ws_size,
                              hipStream_t stream) {
  const float* features    = (const float*)d_in[0];
  const int*   tags        = (const int*)d_in[1];
  const int*   lengths     = (const int*)d_in[2];
  const float* W           = (const float*)d_in[3];
  const float* bias        = (const float*)d_in[4];
  const float* transitions = (const float*)d_in[5];
  float* out   = (float*)d_out;
  float* feats = (float*)d_ws;  // [B*T][8] fp32 = 2 MB

  zero_out_kernel<<<1, 1, 0, stream>>>(out);
  emis_kernel<<<(B_ * T_) / 4, 256, 0, stream>>>(features, W, bias, feats);
  forward_kernel<<<B_ / 8, 64, 0, stream>>>(feats, lengths, transitions, out);
  gold_kernel<<<B_, 64, 0, stream>>>(feats, tags, lengths, transitions, out);
}

// Round 2
// 143.097 us; speedup vs baseline: 1.3795x; 1.3795x over previous
//
#include <hip/hip_runtime.h>

#define B_ 128
#define T_ 512
#define H_ 1024
#define K_ 7
#define START_ 5
#define STOP_ 6
#define LOG2E 1.4426950408889634f
#define LN2 0.6931471805599453f
#define NEG2 (-10000.0f * 1.4426950408889634f)   // -10000 * log2(e)

__device__ __forceinline__ float fexp2(float x) { return __builtin_amdgcn_exp2f(x); }
__device__ __forceinline__ float flog2(float x) { return __builtin_amdgcn_logf(x); }

// ---------------- Kernel 1: emissions (log2-scaled), W in registers ----------------
// e2[b,t,k] = (dot(features[b,t,:], W[k,:]) + bias[k]) * LOG2E, stored [BT][8]
// One wave per row (grid-stride). 10-shuffle multi-value butterfly reduction.
__global__ __launch_bounds__(256) void emis_kernel(
    const float* __restrict__ features, const float* __restrict__ W,
    const float* __restrict__ bias, float* __restrict__ e2, float* __restrict__ out) {
  if (blockIdx.x == 0 && threadIdx.x == 0) out[0] = 0.0f;  // zero scalar output

  const int tid = threadIdx.x;
  const int lane = tid & 63;
  const int gwave = blockIdx.x * 4 + (tid >> 6);
  const int nwaves = gridDim.x * 4;

  // W fragment in registers: w[k][c] = W[k][c*256 + lane*4 .. +3]  (112 VGPRs)
  float4 w[K_][4];
#pragma unroll
  for (int k = 0; k < K_; ++k)
#pragma unroll
    for (int c = 0; c < 4; ++c)
      w[k][c] = *(const float4*)(W + k * H_ + c * 256 + lane * 4);

  // after the butterfly, lane l holds value index v = 4*bit0 | 2*bit1 | bit2
  const int vidx = ((lane & 1) << 2) | (lane & 2) | ((lane >> 2) & 1);
  float myb = 0.0f;
  if (vidx < K_) myb = bias[vidx];

  int row = gwave;
  float4 f0, f1, f2, f3;
  {
    const float4* fp = (const float4*)(features + (size_t)row * H_);
    f0 = fp[lane]; f1 = fp[64 + lane]; f2 = fp[128 + lane]; f3 = fp[192 + lane];
  }

  while (row < B_ * T_) {
    const int nrow = row + nwaves;
    float4 g0, g1, g2, g3;
    if (nrow < B_ * T_) {  // prefetch next row
      const float4* fp = (const float4*)(features + (size_t)nrow * H_);
      g0 = fp[lane]; g1 = fp[64 + lane]; g2 = fp[128 + lane]; g3 = fp[192 + lane];
    }

    float acc[8];
#pragma unroll
    for (int k = 0; k < 8; ++k) acc[k] = 0.0f;
#pragma unroll
    for (int k = 0; k < K_; ++k) {
      acc[k] += f0.x * w[k][0].x + f0.y * w[k][0].y + f0.z * w[k][0].z + f0.w * w[k][0].w;
      acc[k] += f1.x * w[k][1].x + f1.y * w[k][1].y + f1.z * w[k][1].z + f1.w * w[k][1].w;
      acc[k] += f2.x * w[k][2].x + f2.y * w[k][2].y + f2.z * w[k][2].z + f2.w * w[k][2].w;
      acc[k] += f3.x * w[k][3].x + f3.y * w[k][3].y + f3.z * w[k][3].z + f3.w * w[k][3].w;
    }

    // multi-value butterfly: 10 shuffles total for 8 values over 64 lanes
    const bool b0 = lane & 1;
    float k0 = b0 ? acc[4] : acc[0], s0 = b0 ? acc[0] : acc[4];
    float k1 = b0 ? acc[5] : acc[1], s1 = b0 ? acc[1] : acc[5];
    float k2 = b0 ? acc[6] : acc[2], s2 = b0 ? acc[2] : acc[6];
    float k3 = b0 ? acc[7] : acc[3], s3 = b0 ? acc[3] : acc[7];
    k0 += __shfl_xor(s0, 1, 64); k1 += __shfl_xor(s1, 1, 64);
    k2 += __shfl_xor(s2, 1, 64); k3 += __shfl_xor(s3, 1, 64);
    const bool b1 = lane & 2;
    float m0 = b1 ? k2 : k0, t0 = b1 ? k0 : k2;
    float m1 = b1 ? k3 : k1, t1 = b1 ? k1 : k3;
    m0 += __shfl_xor(t0, 2, 64); m1 += __shfl_xor(t1, 2, 64);
    const bool b2 = lane & 4;
    float x = b2 ? m1 : m0, y = b2 ? m0 : m1;
    x += __shfl_xor(y, 4, 64);
    x += __shfl_xor(x, 8, 64);
    x += __shfl_xor(x, 16, 64);
    x += __shfl_xor(x, 32, 64);

    if (lane < 8 && vidx < K_)
      e2[(size_t)row * 8 + vidx] = (x + myb) * LOG2E;

    row = nrow;
    f0 = g0; f1 = g1; f2 = g2; f3 = g3;
  }
}

// ---------------- Kernel 2: pair-compose adjacent steps (log2 domain) ----------------
// M_t[n,p] = e2[t,n] + tr2[n,p] for t<len, else identity (0 diag / NEG2 off-diag).
// M2[b,j,n,p] = log2sumexp2_m( M_{2j+1}[n,m] + M_{2j}[m,p] ),  stored [B][256][7][8].
__global__ __launch_bounds__(256) void pair_kernel(
    const float* __restrict__ e2, const int* __restrict__ lengths,
    const float* __restrict__ transitions, float* __restrict__ M2) {
  const int gid = blockIdx.x * 256 + threadIdx.x;  // = (b*256 + j)*7 + n
  const int n = gid % 7;
  const int bj = gid / 7;
  const int j = bj & 255;
  const int b = bj >> 8;

  const int len = lengths[b];
  const int t0 = 2 * j, t1 = 2 * j + 1;
  const bool a_real = t0 < len, b_real = t1 < len;

  float tr[K_][K_];
#pragma unroll
  for (int m = 0; m < K_; ++m)
#pragma unroll
    for (int p = 0; p < K_; ++p) tr[m][p] = transitions[m * K_ + p] * LOG2E;

  const float* ea = e2 + ((size_t)b * T_ + t0) * 8;
  const float* eb = ea + 8;

  float A[K_][K_];  // first-step matrix
#pragma unroll
  for (int m = 0; m < K_; ++m) {
    const float eam = a_real ? ea[m] : 0.0f;
#pragma unroll
    for (int p = 0; p < K_; ++p)
      A[m][p] = a_real ? (eam + tr[m][p]) : (m == p ? 0.0f : NEG2);
  }
  float Br[K_];  // row n of second-step matrix
  const float ebn = b_real ? eb[n] : 0.0f;
#pragma unroll
  for (int m = 0; m < K_; ++m)
    Br[m] = b_real ? (ebn + tr[n][m]) : (n == m ? 0.0f : NEG2);

  float o[8];
#pragma unroll
  for (int p = 0; p < K_; ++p) {
    float q[K_];
#pragma unroll
    for (int m = 0; m < K_; ++m) q[m] = Br[m] + A[m][p];
    float mx = fmaxf(fmaxf(fmaxf(q[0], q[1]), fmaxf(q[2], q[3])),
                     fmaxf(fmaxf(q[4], q[5]), q[6]));
    float s = 0.0f;
#pragma unroll
    for (int m = 0; m < K_; ++m) s += fexp2(q[m] - mx);
    o[p] = mx + flog2(s);
  }
  o[7] = NEG2;

  float* mp = M2 + (size_t)gid * 8;
  *(float4*)(mp) = make_float4(o[0], o[1], o[2], o[3]);
  *(float4*)(mp + 4) = make_float4(o[4], o[5], o[6], o[7]);
}

// ---------------- Kernel 3: fused forward scan (256 steps) + gold score ----------------
__global__ __launch_bounds__(64) void fg_kernel(
    const float* __restrict__ M2, const float* __restrict__ e2,
    const int* __restrict__ tags, const int* __restrict__ lengths,
    const float* __restrict__ transitions, float* __restrict__ out) {
  if (blockIdx.x < 16) {
    // ---- forward role: 8 batches per block, 8 lanes per batch (lane&7 = next tag) ----
    const int lane = threadIdx.x;
    const int grp = lane >> 3;
    const int nx = lane & 7;
    const int nxc = (nx < K_) ? nx : 0;
    const int batch = blockIdx.x * 8 + grp;
    const int base = grp * 8;

    const float* mp = M2 + (size_t)batch * (256 * K_ * 8) + nxc * 8;

    float fv[K_];
#pragma unroll
    for (int p = 0; p < K_; ++p) fv[p] = (p == START_) ? 0.0f : NEG2;

    // depth-2 prefetch of the 32B matrix row per step
    float4 a0 = *(const float4*)(mp), a1 = *(const float4*)(mp + 4);
    float4 c0 = *(const float4*)(mp + 56), c1 = *(const float4*)(mp + 60);

    for (int j = 0; j < 256; ++j) {
      const int jp = (j + 2 < 256) ? (j + 2) : 255;
      float4 n0 = *(const float4*)(mp + jp * 56);
      float4 n1 = *(const float4*)(mp + jp * 56 + 4);

      const float q0 = a0.x + fv[0], q1 = a0.y + fv[1], q2 = a0.z + fv[2],
                  q3 = a0.w + fv[3], q4 = a1.x + fv[4], q5 = a1.y + fv[5],
                  q6 = a1.z + fv[6];
      const float mx = fmaxf(fmaxf(fmaxf(q0, q1), q2),
                             fmaxf(fmaxf(q3, q4), fmaxf(q5, q6)));
      const float s = fexp2(q0 - mx) + fexp2(q1 - mx) + fexp2(q2 - mx) +
                      fexp2(q3 - mx) + fexp2(q4 - mx) + fexp2(q5 - mx) +
                      fexp2(q6 - mx);
      const float val = mx + flog2(s);
#pragma unroll
      for (int p = 0; p < K_; ++p) fv[p] = __shfl(val, base + p, 64);

      a0 = c0; a1 = c1; c0 = n0; c1 = n1;
    }

    if (nx == 0) {
      float tt[K_];
#pragma unroll
      for (int p = 0; p < K_; ++p)
        tt[p] = fv[p] + transitions[STOP_ * K_ + p] * LOG2E;
      float mx = tt[0];
#pragma unroll
      for (int p = 1; p < K_; ++p) mx = fmaxf(mx, tt[p]);
      float s = 0.0f;
#pragma unroll
      for (int p = 0; p < K_; ++p) s += fexp2(tt[p] - mx);
      atomicAdd(out, (mx + flog2(s)) * LN2);
    }
  } else {
    // ---- gold role: one block (64 lanes) per batch ----
    const int b = blockIdx.x - 16;
    const int lane = threadIdx.x;
    const int len = lengths[b];
    const int* tg = tags + (size_t)b * T_;
    const float* ep = e2 + (size_t)b * T_ * 8;

    float partial = 0.0f;
    for (int t = lane; t < len; t += 64) {
      const int tag = tg[t];
      partial += ep[t * 8 + tag];                       // emission (log2-scaled)
      const int prev = (t == 0) ? START_ : tg[t - 1];
      partial += transitions[tag * K_ + prev] * LOG2E;  // transition prev->tag
    }
#pragma unroll
    for (int off = 32; off > 0; off >>= 1) partial += __shfl_xor(partial, off, 64);

    if (lane == 0) {
      partial += transitions[STOP_ * K_ + tg[len - 1]] * LOG2E;
      atomicAdd(out, -partial * LN2);
    }
  }
}

extern "C" void kernel_launch(void* const* d_in, const int* in_sizes, int n_in,
                              void* d_out, int out_size, void* d_ws, size_t ws_size,
                              hipStream_t stream) {
  const float* features    = (const float*)d_in[0];
  const int*   tags        = (const int*)d_in[1];
  const int*   lengths     = (const int*)d_in[2];
  const float* W           = (const float*)d_in[3];
  const float* bias        = (const float*)d_in[4];
  const float* transitions = (const float*)d_in[5];
  float* out = (float*)d_out;
  float* e2  = (float*)d_ws;                                  // [B*T][8] = 2 MB
  float* M2  = (float*)((char*)d_ws + (size_t)B_ * T_ * 8 * 4);  // [B][256][7][8] = 7.34 MB

  emis_kernel<<<1024, 256, 0, stream>>>(features, W, bias, e2, out);
  pair_kernel<<<(B_ * 256 * K_) / 256, 256, 0, stream>>>(e2, lengths, transitions, M2);
  fg_kernel<<<16 + B_, 64, 0, stream>>>(M2, e2, tags, lengths, transitions, out);
}

// Round 3
// 68.040 us; speedup vs baseline: 2.9013x; 2.1031x over previous
//
#include <hip/hip_runtime.h>

#define B_ 128
#define T_ 512
#define H_ 1024
#define K_ 7
#define START_ 5
#define STOP_ 6
#define LOG2E 1.4426950408889634f
#define LN2 0.6931471805599453f
#define NEG2 (-10000.0f * 1.4426950408889634f)   // -10000 * log2(e)
#define MS 57   // LDS matrix stride in floats (odd -> conflict-spread)

__device__ __forceinline__ float fexp2(float x) { return __builtin_amdgcn_exp2f(x); }
__device__ __forceinline__ float flog2(float x) { return __builtin_amdgcn_logf(x); }

// ---------------- Kernel 1: emissions (log2-scaled), W in registers ----------------
__global__ __launch_bounds__(256) void emis_kernel(
    const float* __restrict__ features, const float* __restrict__ W,
    const float* __restrict__ bias, float* __restrict__ e2, float* __restrict__ out) {
  if (blockIdx.x == 0 && threadIdx.x == 0) out[0] = 0.0f;  // zero scalar output

  const int tid = threadIdx.x;
  const int lane = tid & 63;
  const int gwave = blockIdx.x * 4 + (tid >> 6);
  const int nwaves = gridDim.x * 4;

  float4 w[K_][4];
#pragma unroll
  for (int k = 0; k < K_; ++k)
#pragma unroll
    for (int c = 0; c < 4; ++c)
      w[k][c] = *(const float4*)(W + k * H_ + c * 256 + lane * 4);

  const int vidx = ((lane & 1) << 2) | (lane & 2) | ((lane >> 2) & 1);
  float myb = 0.0f;
  if (vidx < K_) myb = bias[vidx];

  int row = gwave;
  float4 f0, f1, f2, f3;
  {
    const float4* fp = (const float4*)(features + (size_t)row * H_);
    f0 = fp[lane]; f1 = fp[64 + lane]; f2 = fp[128 + lane]; f3 = fp[192 + lane];
  }

  while (row < B_ * T_) {
    const int nrow = row + nwaves;
    float4 g0, g1, g2, g3;
    if (nrow < B_ * T_) {
      const float4* fp = (const float4*)(features + (size_t)nrow * H_);
      g0 = fp[lane]; g1 = fp[64 + lane]; g2 = fp[128 + lane]; g3 = fp[192 + lane];
    }

    float acc[8];
#pragma unroll
    for (int k = 0; k < 8; ++k) acc[k] = 0.0f;
#pragma unroll
    for (int k = 0; k < K_; ++k) {
      acc[k] += f0.x * w[k][0].x + f0.y * w[k][0].y + f0.z * w[k][0].z + f0.w * w[k][0].w;
      acc[k] += f1.x * w[k][1].x + f1.y * w[k][1].y + f1.z * w[k][1].z + f1.w * w[k][1].w;
      acc[k] += f2.x * w[k][2].x + f2.y * w[k][2].y + f2.z * w[k][2].z + f2.w * w[k][2].w;
      acc[k] += f3.x * w[k][3].x + f3.y * w[k][3].y + f3.z * w[k][3].z + f3.w * w[k][3].w;
    }

    // multi-value butterfly: 10 shuffles for 8 values over 64 lanes
    const bool b0 = lane & 1;
    float k0 = b0 ? acc[4] : acc[0], s0 = b0 ? acc[0] : acc[4];
    float k1 = b0 ? acc[5] : acc[1], s1 = b0 ? acc[1] : acc[5];
    float k2 = b0 ? acc[6] : acc[2], s2 = b0 ? acc[2] : acc[6];
    float k3 = b0 ? acc[7] : acc[3], s3 = b0 ? acc[3] : acc[7];
    k0 += __shfl_xor(s0, 1, 64); k1 += __shfl_xor(s1, 1, 64);
    k2 += __shfl_xor(s2, 1, 64); k3 += __shfl_xor(s3, 1, 64);
    const bool b1 = lane & 2;
    float m0 = b1 ? k2 : k0, t0 = b1 ? k0 : k2;
    float m1 = b1 ? k3 : k1, t1 = b1 ? k1 : k3;
    m0 += __shfl_xor(t0, 2, 64); m1 += __shfl_xor(t1, 2, 64);
    const bool b2 = lane & 4;
    float x = b2 ? m1 : m0, y = b2 ? m0 : m1;
    x += __shfl_xor(y, 4, 64);
    x += __shfl_xor(x, 8, 64);
    x += __shfl_xor(x, 16, 64);
    x += __shfl_xor(x, 32, 64);

    if (lane < 8 && vidx < K_)
      e2[(size_t)row * 8 + vidx] = (x + myb) * LOG2E;

    row = nrow;
    f0 = g0; f1 = g1; f2 = g2; f3 = g3;
  }
}

// ---------------- tree-compose level: NM output mats from 2*NM input mats ----------------
// out[q] = odd[q] (*) even[q] where (*) is log2-matmul; compute-all -> barrier -> write.
template <int NM>
__device__ __forceinline__ void level_fn(const float* __restrict__ evenB,
                                         const float* __restrict__ oddB,
                                         int qstride, float* __restrict__ dst,
                                         int tid) {
  constexpr int TOT = NM * 49;
  constexpr int NI = (TOT + 255) / 256;
  float tmp[NI];
#pragma unroll
  for (int i = 0; i < NI; ++i) {
    const int u = tid + i * 256;
    if (u < TOT) {
      const int q = u / 49, r = u - 49 * q, n = r / 7, p = r - 7 * n;
      const float* hi = oddB + q * qstride;
      const float* lo = evenB + q * qstride;
      float qq[7];
#pragma unroll
      for (int m = 0; m < 7; ++m) qq[m] = hi[n * 8 + m] + lo[m * 8 + p];
      float mx = fmaxf(fmaxf(fmaxf(qq[0], qq[1]), fmaxf(qq[2], qq[3])),
                       fmaxf(fmaxf(qq[4], qq[5]), qq[6]));
      float s = 0.f;
#pragma unroll
      for (int m = 0; m < 7; ++m) s += fexp2(qq[m] - mx);
      tmp[i] = mx + flog2(s);
    }
  }
  __syncthreads();
#pragma unroll
  for (int i = 0; i < NI; ++i) {
    const int u = tid + i * 256;
    if (u < TOT) {
      const int q = u / 49, r = u - 49 * q, n = r / 7, p = r - 7 * n;
      dst[q * MS + n * 8 + p] = tmp[i];
    }
  }
  __syncthreads();
}

// ---------------- Kernel 2: per-batch tree scan + gold, all in LDS ----------------
__global__ __launch_bounds__(256) void scan_kernel(
    const float* __restrict__ e2, const int* __restrict__ tags,
    const int* __restrict__ lengths, const float* __restrict__ transitions,
    float* __restrict__ out) {
  __shared__ float s0[128 * MS];   // 29184 B
  __shared__ float s1[128 * MS];   // 29184 B
  __shared__ float tr2s[49];
  __shared__ float red[4];

  const int tid = threadIdx.x;
  const int b = blockIdx.x;
  const int len = lengths[b];

  if (tid < 49) tr2s[tid] = transitions[tid] * LOG2E;
  __syncthreads();

  // ---- gold partial: 2 timesteps per thread ----
  const int* tg = tags + (size_t)b * T_;
  const float* ep = e2 + (size_t)b * T_ * 8;
  float gp = 0.f;
  for (int t = tid; t < len; t += 256) {
    const int tag = tg[t];
    const int prev = t ? tg[t - 1] : START_;
    gp += ep[(size_t)t * 8 + tag] + tr2s[tag * 7 + prev];
  }
#pragma unroll
  for (int off = 32; off; off >>= 1) gp += __shfl_xor(gp, off, 64);
  if ((tid & 63) == 0) red[tid >> 6] = gp;

  // ---- pair phase: thread tid builds pair-matrix for steps (2*tid, 2*tid+1) ----
  {
    const int t0 = 2 * tid, t1 = 2 * tid + 1;
    float P[7][7];
    if (t1 < len) {
      const float* e0p = ep + (size_t)t0 * 8;
      float c[7], e1[7];
#pragma unroll
      for (int m = 0; m < 7; ++m) c[m] = e0p[m];
#pragma unroll
      for (int n = 0; n < 7; ++n) e1[n] = e0p[8 + n];
#pragma unroll
      for (int n = 0; n < 7; ++n) {
        float a[7];
#pragma unroll
        for (int m = 0; m < 7; ++m) a[m] = tr2s[n * 7 + m] + c[m];
#pragma unroll
        for (int p = 0; p < 7; ++p) {
          float q[7];
#pragma unroll
          for (int m = 0; m < 7; ++m) q[m] = a[m] + tr2s[m * 7 + p];
          float mx = fmaxf(fmaxf(fmaxf(q[0], q[1]), fmaxf(q[2], q[3])),
                           fmaxf(fmaxf(q[4], q[5]), q[6]));
          float s = 0.f;
#pragma unroll
          for (int m = 0; m < 7; ++m) s += fexp2(q[m] - mx);
          P[n][p] = e1[n] + mx + flog2(s);
        }
      }
    } else if (t0 < len) {
      const float* e0p = ep + (size_t)t0 * 8;
#pragma unroll
      for (int n = 0; n < 7; ++n) {
        const float e0n = e0p[n];
#pragma unroll
        for (int p = 0; p < 7; ++p) P[n][p] = e0n + tr2s[n * 7 + p];
      }
    } else {
#pragma unroll
      for (int n = 0; n < 7; ++n)
#pragma unroll
        for (int p = 0; p < 7; ++p) P[n][p] = (n == p) ? 0.f : NEG2;
    }
    float* dstm = ((tid & 1) ? s1 : s0) + (tid >> 1) * MS;
#pragma unroll
    for (int n = 0; n < 7; ++n)
#pragma unroll
      for (int p = 0; p < 7; ++p) dstm[n * 8 + p] = P[n][p];
  }
  __syncthreads();

  // ---- tree reduction: 256 -> 128 -> ... -> 1 ----
  level_fn<128>(s0, s1, MS, s0, tid);            // pairs (even in s0, odd in s1) -> s0
  level_fn<64>(s0, s0 + MS, 2 * MS, s1, tid);
  level_fn<32>(s1, s1 + MS, 2 * MS, s0, tid);
  level_fn<16>(s0, s0 + MS, 2 * MS, s1, tid);
  level_fn<8>(s1, s1 + MS, 2 * MS, s0, tid);
  level_fn<4>(s0, s0 + MS, 2 * MS, s1, tid);
  level_fn<2>(s1, s1 + MS, 2 * MS, s0, tid);
  level_fn<1>(s0, s0 + MS, 2 * MS, s1, tid);     // final matrix in s1[0..]

  // ---- terminal + combine ----
  if (tid == 0) {
    float tt[7];
#pragma unroll
    for (int n = 0; n < 7; ++n) tt[n] = s1[n * 8 + START_] + tr2s[STOP_ * 7 + n];
    float mx = tt[0];
#pragma unroll
    for (int n = 1; n < 7; ++n) mx = fmaxf(mx, tt[n]);
    float s = 0.f;
#pragma unroll
    for (int n = 0; n < 7; ++n) s += fexp2(tt[n] - mx);
    const float fwd = mx + flog2(s);
    const float gold = red[0] + red[1] + red[2] + red[3] +
                       tr2s[STOP_ * 7 + tg[len - 1]];
    atomicAdd(out, (fwd - gold) * LN2);
  }
}

extern "C" void kernel_launch(void* const* d_in, const int* in_sizes, int n_in,
                              void* d_out, int out_size, void* d_ws, size_t ws_size,
                              hipStream_t stream) {
  const float* features    = (const float*)d_in[0];
  const int*   tags        = (const int*)d_in[1];
  const int*   lengths     = (const int*)d_in[2];
  const float* W           = (const float*)d_in[3];
  const float* bias        = (const float*)d_in[4];
  const float* transitions = (const float*)d_in[5];
  float* out = (float*)d_out;
  float* e2  = (float*)d_ws;  // [B*T][8] fp32 = 2 MB

  emis_kernel<<<1024, 256, 0, stream>>>(features, W, bias, e2, out);
  scan_kernel<<<B_, 256, 0, stream>>>(e2, tags, lengths, transitions, out);
}

// Round 4
// 63.869 us; speedup vs baseline: 3.0908x; 1.0653x over previous
//
#include <hip/hip_runtime.h>

#define B_ 128
#define T_ 512
#define H_ 1024
#define K_ 7
#define START_ 5
#define STOP_ 6
#define LOG2E 1.4426950408889634f
#define LN2 0.6931471805599453f
#define NEG2 (-10000.0f * 1.4426950408889634f)   // -10000 * log2(e)
#define MS 57   // LDS matrix stride in floats (odd -> conflict-spread)

__device__ __forceinline__ float fexp2(float x) { return __builtin_amdgcn_exp2f(x); }
__device__ __forceinline__ float flog2(float x) { return __builtin_amdgcn_logf(x); }

// ---------------- Kernel 1: emissions (log2-scaled), W in registers ----------------
// Grid 2048 x 256: 8192 waves, each owns exactly 8 rows (stride 8192).
// Depth-2 row prefetch; fully unrolled so guards are compile-time and buffer
// rotation is register renaming (no v_mov chains).
__global__ __launch_bounds__(256, 2) void emis_kernel(
    const float* __restrict__ features, const float* __restrict__ W,
    const float* __restrict__ bias, float* __restrict__ e2, float* __restrict__ out) {
  if (blockIdx.x == 0 && threadIdx.x == 0) out[0] = 0.0f;  // zero scalar output

  const int tid = threadIdx.x;
  const int lane = tid & 63;
  const int gwave = blockIdx.x * 4 + (tid >> 6);   // 0..8191
  const int NW = 8192;

  // W fragment in registers: w[k][c] = W[k][c*256 + lane*4 .. +3]  (112 VGPRs)
  float4 w[K_][4];
#pragma unroll
  for (int k = 0; k < K_; ++k)
#pragma unroll
    for (int c = 0; c < 4; ++c)
      w[k][c] = *(const float4*)(W + k * H_ + c * 256 + lane * 4);

  // after the butterfly, lane l holds value index v = 4*bit0 | 2*bit1 | bit2
  const int vidx = ((lane & 1) << 2) | (lane & 2) | ((lane >> 2) & 1);
  float myb = 0.0f;
  if (vidx < K_) myb = bias[vidx];

  float4 A0, A1, A2, A3, B0, B1, B2, B3;
  {
    const float4* fp = (const float4*)(features + (size_t)gwave * H_);
    A0 = fp[lane]; A1 = fp[64 + lane]; A2 = fp[128 + lane]; A3 = fp[192 + lane];
    const float4* gp = (const float4*)(features + (size_t)(gwave + NW) * H_);
    B0 = gp[lane]; B1 = gp[64 + lane]; B2 = gp[128 + lane]; B3 = gp[192 + lane];
  }

#pragma unroll
  for (int it = 0; it < 8; ++it) {
    const int cur = gwave + it * NW;
    float4 C0, C1, C2, C3;
    if (it < 6) {  // compile-time guard after unroll
      const float4* pp = (const float4*)(features + (size_t)(cur + 2 * NW) * H_);
      C0 = pp[lane]; C1 = pp[64 + lane]; C2 = pp[128 + lane]; C3 = pp[192 + lane];
    }

    float acc[8];
#pragma unroll
    for (int k = 0; k < 8; ++k) acc[k] = 0.0f;
#pragma unroll
    for (int k = 0; k < K_; ++k) {
      acc[k] += A0.x * w[k][0].x + A0.y * w[k][0].y + A0.z * w[k][0].z + A0.w * w[k][0].w;
      acc[k] += A1.x * w[k][1].x + A1.y * w[k][1].y + A1.z * w[k][1].z + A1.w * w[k][1].w;
      acc[k] += A2.x * w[k][2].x + A2.y * w[k][2].y + A2.z * w[k][2].z + A2.w * w[k][2].w;
      acc[k] += A3.x * w[k][3].x + A3.y * w[k][3].y + A3.z * w[k][3].z + A3.w * w[k][3].w;
    }

    // multi-value butterfly: 10 shuffles for 8 values over 64 lanes
    const bool b0 = lane & 1;
    float k0 = b0 ? acc[4] : acc[0], s0 = b0 ? acc[0] : acc[4];
    float k1 = b0 ? acc[5] : acc[1], s1 = b0 ? acc[1] : acc[5];
    float k2 = b0 ? acc[6] : acc[2], s2 = b0 ? acc[2] : acc[6];
    float k3 = b0 ? acc[7] : acc[3], s3 = b0 ? acc[3] : acc[7];
    k0 += __shfl_xor(s0, 1, 64); k1 += __shfl_xor(s1, 1, 64);
    k2 += __shfl_xor(s2, 1, 64); k3 += __shfl_xor(s3, 1, 64);
    const bool b1 = lane & 2;
    float m0 = b1 ? k2 : k0, t0 = b1 ? k0 : k2;
    float m1 = b1 ? k3 : k1, t1 = b1 ? k1 : k3;
    m0 += __shfl_xor(t0, 2, 64); m1 += __shfl_xor(t1, 2, 64);
    const bool b2 = lane & 4;
    float x = b2 ? m1 : m0, y = b2 ? m0 : m1;
    x += __shfl_xor(y, 4, 64);
    x += __shfl_xor(x, 8, 64);
    x += __shfl_xor(x, 16, 64);
    x += __shfl_xor(x, 32, 64);

    if (lane < 8 && vidx < K_)
      e2[(size_t)cur * 8 + vidx] = (x + myb) * LOG2E;

    // rotate buffers (register renaming under full unroll)
    A0 = B0; A1 = B1; A2 = B2; A3 = B3;
    if (it < 6) { B0 = C0; B1 = C1; B2 = C2; B3 = C3; }
  }
}

// ---------------- tree-compose level: NM output mats from 2*NM input mats ----------------
template <int NM>
__device__ __forceinline__ void level_fn(const float* __restrict__ evenB,
                                         const float* __restrict__ oddB,
                                         int qstride, float* __restrict__ dst,
                                         int tid) {
  constexpr int TOT = NM * 49;
  constexpr int NI = (TOT + 255) / 256;
  float tmp[NI];
#pragma unroll
  for (int i = 0; i < NI; ++i) {
    const int u = tid + i * 256;
    if (u < TOT) {
      const int q = u / 49, r = u - 49 * q, n = r / 7, p = r - 7 * n;
      const float* hi = oddB + q * qstride;
      const float* lo = evenB + q * qstride;
      float qq[7];
#pragma unroll
      for (int m = 0; m < 7; ++m) qq[m] = hi[n * 8 + m] + lo[m * 8 + p];
      float mx = fmaxf(fmaxf(fmaxf(qq[0], qq[1]), fmaxf(qq[2], qq[3])),
                       fmaxf(fmaxf(qq[4], qq[5]), qq[6]));
      float s = 0.f;
#pragma unroll
      for (int m = 0; m < 7; ++m) s += fexp2(qq[m] - mx);
      tmp[i] = mx + flog2(s);
    }
  }
  __syncthreads();
#pragma unroll
  for (int i = 0; i < NI; ++i) {
    const int u = tid + i * 256;
    if (u < TOT) {
      const int q = u / 49, r = u - 49 * q, n = r / 7, p = r - 7 * n;
      dst[q * MS + n * 8 + p] = tmp[i];
    }
  }
  __syncthreads();
}

// ---------------- Kernel 2: per-batch tree scan + gold, all in LDS ----------------
__global__ __launch_bounds__(256) void scan_kernel(
    const float* __restrict__ e2, const int* __restrict__ tags,
    const int* __restrict__ lengths, const float* __restrict__ transitions,
    float* __restrict__ out) {
  __shared__ float s0[128 * MS];   // 29184 B
  __shared__ float s1[128 * MS];   // 29184 B
  __shared__ float tr2s[49];
  __shared__ float red[4];

  const int tid = threadIdx.x;
  const int b = blockIdx.x;
  const int len = lengths[b];

  if (tid < 49) tr2s[tid] = transitions[tid] * LOG2E;
  __syncthreads();

  // ---- gold partial ----
  const int* tg = tags + (size_t)b * T_;
  const float* ep = e2 + (size_t)b * T_ * 8;
  float gp = 0.f;
  for (int t = tid; t < len; t += 256) {
    const int tag = tg[t];
    const int prev = t ? tg[t - 1] : START_;
    gp += ep[(size_t)t * 8 + tag] + tr2s[tag * 7 + prev];
  }
#pragma unroll
  for (int off = 32; off; off >>= 1) gp += __shfl_xor(gp, off, 64);
  if ((tid & 63) == 0) red[tid >> 6] = gp;

  // ---- pair phase: thread tid builds pair-matrix for steps (2*tid, 2*tid+1) ----
  {
    const int t0 = 2 * tid, t1 = 2 * tid + 1;
    float P[7][7];
    if (t1 < len) {
      const float* e0p = ep + (size_t)t0 * 8;
      float c[7], e1[7];
#pragma unroll
      for (int m = 0; m < 7; ++m) c[m] = e0p[m];
#pragma unroll
      for (int n = 0; n < 7; ++n) e1[n] = e0p[8 + n];
#pragma unroll
      for (int n = 0; n < 7; ++n) {
        float a[7];
#pragma unroll
        for (int m = 0; m < 7; ++m) a[m] = tr2s[n * 7 + m] + c[m];
#pragma unroll
        for (int p = 0; p < 7; ++p) {
          float q[7];
#pragma unroll
          for (int m = 0; m < 7; ++m) q[m] = a[m] + tr2s[m * 7 + p];
          float mx = fmaxf(fmaxf(fmaxf(q[0], q[1]), fmaxf(q[2], q[3])),
                           fmaxf(fmaxf(q[4], q[5]), q[6]));
          float s = 0.f;
#pragma unroll
          for (int m = 0; m < 7; ++m) s += fexp2(q[m] - mx);
          P[n][p] = e1[n] + mx + flog2(s);
        }
      }
    } else if (t0 < len) {
      const float* e0p = ep + (size_t)t0 * 8;
#pragma unroll
      for (int n = 0; n < 7; ++n) {
        const float e0n = e0p[n];
#pragma unroll
        for (int p = 0; p < 7; ++p) P[n][p] = e0n + tr2s[n * 7 + p];
      }
    } else {
#pragma unroll
      for (int n = 0; n < 7; ++n)
#pragma unroll
        for (int p = 0; p < 7; ++p) P[n][p] = (n == p) ? 0.f : NEG2;
    }
    float* dstm = ((tid & 1) ? s1 : s0) + (tid >> 1) * MS;
#pragma unroll
    for (int n = 0; n < 7; ++n)
#pragma unroll
      for (int p = 0; p < 7; ++p) dstm[n * 8 + p] = P[n][p];
  }
  __syncthreads();

  // ---- tree reduction: 256 -> 128 -> ... -> 1 ----
  level_fn<128>(s0, s1, MS, s0, tid);
  level_fn<64>(s0, s0 + MS, 2 * MS, s1, tid);
  level_fn<32>(s1, s1 + MS, 2 * MS, s0, tid);
  level_fn<16>(s0, s0 + MS, 2 * MS, s1, tid);
  level_fn<8>(s1, s1 + MS, 2 * MS, s0, tid);
  level_fn<4>(s0, s0 + MS, 2 * MS, s1, tid);
  level_fn<2>(s1, s1 + MS, 2 * MS, s0, tid);
  level_fn<1>(s0, s0 + MS, 2 * MS, s1, tid);     // final matrix in s1[0..]

  // ---- terminal + combine ----
  if (tid == 0) {
    float tt[7];
#pragma unroll
    for (int n = 0; n < 7; ++n) tt[n] = s1[n * 8 + START_] + tr2s[STOP_ * 7 + n];
    float mx = tt[0];
#pragma unroll
    for (int n = 1; n < 7; ++n) mx = fmaxf(mx, tt[n]);
    float s = 0.f;
#pragma unroll
    for (int n = 0; n < 7; ++n) s += fexp2(tt[n] - mx);
    const float fwd = mx + flog2(s);
    const float gold = red[0] + red[1] + red[2] + red[3] +
                       tr2s[STOP_ * 7 + tg[len - 1]];
    atomicAdd(out, (fwd - gold) * LN2);
  }
}

extern "C" void kernel_launch(void* const* d_in, const int* in_sizes, int n_in,
                              void* d_out, int out_size, void* d_ws, size_t ws_size,
                              hipStream_t stream) {
  const float* features    = (const float*)d_in[0];
  const int*   tags        = (const int*)d_in[1];
  const int*   lengths     = (const int*)d_in[2];
  const float* W           = (const float*)d_in[3];
  const float* bias        = (const float*)d_in[4];
  const float* transitions = (const float*)d_in[5];
  float* out = (float*)d_out;
  float* e2  = (float*)d_ws;  // [B*T][8] fp32 = 2 MB

  emis_kernel<<<2048, 256, 0, stream>>>(features, W, bias, e2, out);
  scan_kernel<<<B_, 256, 0, stream>>>(e2, tags, lengths, transitions, out);
}

// Round 5
// 63.122 us; speedup vs baseline: 3.1274x; 1.0118x over previous
//
#include <hip/hip_runtime.h>

#define B_ 128
#define T_ 512
#define H_ 1024
#define K_ 7
#define START_ 5
#define STOP_ 6
#define LOG2E 1.4426950408889634f
#define LN2 0.6931471805599453f
#define NEG2 (-10000.0f * 1.4426950408889634f)   // -10000 * log2(e)
#define MS 57   // LDS matrix stride in floats (odd -> conflict-spread)

typedef float f32x4 __attribute__((ext_vector_type(4)));

__device__ __forceinline__ float fexp2(float x) { return __builtin_amdgcn_exp2f(x); }
__device__ __forceinline__ float flog2(float x) { return __builtin_amdgcn_logf(x); }
__device__ __forceinline__ f32x4 ntload(const float* p) {
  return __builtin_nontemporal_load((const f32x4*)p);
}

// ---------------- Kernel 1: emissions (log2-scaled), W in registers ----------------
// Grid 2048 x 256: 8192 waves, each owns exactly 8 rows (stride 8192).
// Depth-3 row prefetch (~1000 cyc lead vs ~900 cyc HBM latency); nontemporal
// feature loads (pure streaming). Fully unrolled: guards compile-time.
__global__ __launch_bounds__(256, 2) void emis_kernel(
    const float* __restrict__ features, const float* __restrict__ W,
    const float* __restrict__ bias, float* __restrict__ e2, float* __restrict__ out) {
  if (blockIdx.x == 0 && threadIdx.x == 0) out[0] = 0.0f;  // zero scalar output

  const int tid = threadIdx.x;
  const int lane = tid & 63;
  const int gwave = blockIdx.x * 4 + (tid >> 6);   // 0..8191
  const int NW = 8192;

  // W fragment in registers: w[k][c] = W[k][c*256 + lane*4 .. +3]  (112 VGPRs)
  f32x4 w[K_][4];
#pragma unroll
  for (int k = 0; k < K_; ++k)
#pragma unroll
    for (int c = 0; c < 4; ++c)
      w[k][c] = *(const f32x4*)(W + k * H_ + c * 256 + lane * 4);

  // after the butterfly, lane l holds value index v = 4*bit0 | 2*bit1 | bit2
  const int vidx = ((lane & 1) << 2) | (lane & 2) | ((lane >> 2) & 1);
  float myb = 0.0f;
  if (vidx < K_) myb = bias[vidx];

  f32x4 A0, A1, A2, A3, B0, B1, B2, B3, C0, C1, C2, C3;
  {
    const float* fp = features + (size_t)gwave * H_ + lane * 4;
    A0 = ntload(fp); A1 = ntload(fp + 256); A2 = ntload(fp + 512); A3 = ntload(fp + 768);
    const float* gp = fp + (size_t)NW * H_;
    B0 = ntload(gp); B1 = ntload(gp + 256); B2 = ntload(gp + 512); B3 = ntload(gp + 768);
    const float* hp = gp + (size_t)NW * H_;
    C0 = ntload(hp); C1 = ntload(hp + 256); C2 = ntload(hp + 512); C3 = ntload(hp + 768);
  }

#pragma unroll
  for (int it = 0; it < 8; ++it) {
    const int cur = gwave + it * NW;
    f32x4 D0, D1, D2, D3;
    if (it < 5) {  // compile-time guard after unroll: prefetch row it+3
      const float* pp = features + (size_t)(cur + 3 * NW) * H_ + lane * 4;
      D0 = ntload(pp); D1 = ntload(pp + 256); D2 = ntload(pp + 512); D3 = ntload(pp + 768);
    }

    float acc[8];
#pragma unroll
    for (int k = 0; k < 8; ++k) acc[k] = 0.0f;
#pragma unroll
    for (int k = 0; k < K_; ++k) {
      acc[k] += A0.x * w[k][0].x + A0.y * w[k][0].y + A0.z * w[k][0].z + A0.w * w[k][0].w;
      acc[k] += A1.x * w[k][1].x + A1.y * w[k][1].y + A1.z * w[k][1].z + A1.w * w[k][1].w;
      acc[k] += A2.x * w[k][2].x + A2.y * w[k][2].y + A2.z * w[k][2].z + A2.w * w[k][2].w;
      acc[k] += A3.x * w[k][3].x + A3.y * w[k][3].y + A3.z * w[k][3].z + A3.w * w[k][3].w;
    }

    // multi-value butterfly: 10 shuffles for 8 values over 64 lanes
    const bool b0 = lane & 1;
    float k0 = b0 ? acc[4] : acc[0], s0 = b0 ? acc[0] : acc[4];
    float k1 = b0 ? acc[5] : acc[1], s1 = b0 ? acc[1] : acc[5];
    float k2 = b0 ? acc[6] : acc[2], s2 = b0 ? acc[2] : acc[6];
    float k3 = b0 ? acc[7] : acc[3], s3 = b0 ? acc[3] : acc[7];
    k0 += __shfl_xor(s0, 1, 64); k1 += __shfl_xor(s1, 1, 64);
    k2 += __shfl_xor(s2, 1, 64); k3 += __shfl_xor(s3, 1, 64);
    const bool b1 = lane & 2;
    float m0 = b1 ? k2 : k0, t0 = b1 ? k0 : k2;
    float m1 = b1 ? k3 : k1, t1 = b1 ? k1 : k3;
    m0 += __shfl_xor(t0, 2, 64); m1 += __shfl_xor(t1, 2, 64);
    const bool b2 = lane & 4;
    float x = b2 ? m1 : m0, y = b2 ? m0 : m1;
    x += __shfl_xor(y, 4, 64);
    x += __shfl_xor(x, 8, 64);
    x += __shfl_xor(x, 16, 64);
    x += __shfl_xor(x, 32, 64);

    if (lane < 8 && vidx < K_)
      e2[(size_t)cur * 8 + vidx] = (x + myb) * LOG2E;

    // rotate buffers (register renaming under full unroll)
    A0 = B0; A1 = B1; A2 = B2; A3 = B3;
    B0 = C0; B1 = C1; B2 = C2; B3 = C3;
    if (it < 5) { C0 = D0; C1 = D1; C2 = D2; C3 = D3; }
  }
}

// ---------------- tree-compose level: NM outputs from 2*NM inputs, 512 threads ----------------
template <int NM>
__device__ __forceinline__ void level_fn(const float* __restrict__ evenB,
                                         const float* __restrict__ oddB,
                                         int qstride, float* __restrict__ dst,
                                         int tid) {
  constexpr int TOT = NM * 49;
  constexpr int NI = (TOT + 511) / 512;
  float tmp[NI];
#pragma unroll
  for (int i = 0; i < NI; ++i) {
    const int u = tid + i * 512;
    if (u < TOT) {
      const int q = u / 49, r = u - 49 * q, n = r / 7, p = r - 7 * n;
      const float* hi = oddB + q * qstride;
      const float* lo = evenB + q * qstride;
      float qq[7];
#pragma unroll
      for (int m = 0; m < 7; ++m) qq[m] = hi[n * 8 + m] + lo[m * 8 + p];
      float mx = fmaxf(fmaxf(fmaxf(qq[0], qq[1]), fmaxf(qq[2], qq[3])),
                       fmaxf(fmaxf(qq[4], qq[5]), qq[6]));
      float s = 0.f;
#pragma unroll
      for (int m = 0; m < 7; ++m) s += fexp2(qq[m] - mx);
      tmp[i] = mx + flog2(s);
    }
  }
  __syncthreads();
#pragma unroll
  for (int i = 0; i < NI; ++i) {
    const int u = tid + i * 512;
    if (u < TOT) {
      const int q = u / 49, r = u - 49 * q, n = r / 7, p = r - 7 * n;
      dst[q * MS + n * 8 + p] = tmp[i];
    }
  }
  __syncthreads();
}

// ---------------- Kernel 2: per-batch tree scan + gold, 512 threads ----------------
// Waves 0-3: pair phase (no-max logsumexp, values bounded ~±25 in log2 domain).
// Waves 4-7: gold score, concurrent. Then all 8 waves run the tree levels.
__global__ __launch_bounds__(512) void scan_kernel(
    const float* __restrict__ e2, const int* __restrict__ tags,
    const int* __restrict__ lengths, const float* __restrict__ transitions,
    float* __restrict__ out) {
  __shared__ float s0[128 * MS];   // 29184 B
  __shared__ float s1[128 * MS];   // 29184 B
  __shared__ float tr2s[49];
  __shared__ float red[4];

  const int tid = threadIdx.x;
  const int b = blockIdx.x;
  const int len = lengths[b];

  if (tid < 49) tr2s[tid] = transitions[tid] * LOG2E;
  __syncthreads();

  const int* tg = tags + (size_t)b * T_;
  const float* ep = e2 + (size_t)b * T_ * 8;

  if (tid < 256) {
    // ---- pair phase: thread tid builds pair-matrix for steps (2*tid, 2*tid+1) ----
    const int t0 = 2 * tid, t1 = 2 * tid + 1;
    float P[7][7];
    if (t1 < len) {
      const float* e0p = ep + (size_t)t0 * 8;
      float c[7], e1[7];
#pragma unroll
      for (int m = 0; m < 7; ++m) c[m] = e0p[m];
#pragma unroll
      for (int n = 0; n < 7; ++n) e1[n] = e0p[8 + n];
#pragma unroll
      for (int n = 0; n < 7; ++n) {
        float a[7];
#pragma unroll
        for (int m = 0; m < 7; ++m) a[m] = tr2s[n * 7 + m] + c[m];
#pragma unroll
        for (int p = 0; p < 7; ++p) {
          // no-max logsumexp: |finite q| <= ~25 in log2 domain; NEG entries
          // underflow to 0 and the +1e-37 keeps all-underflow rows finite.
          float s = 1e-37f;
#pragma unroll
          for (int m = 0; m < 7; ++m) s += fexp2(a[m] + tr2s[m * 7 + p]);
          P[n][p] = e1[n] + flog2(s);
        }
      }
    } else if (t0 < len) {
      const float* e0p = ep + (size_t)t0 * 8;
#pragma unroll
      for (int n = 0; n < 7; ++n) {
        const float e0n = e0p[n];
#pragma unroll
        for (int p = 0; p < 7; ++p) P[n][p] = e0n + tr2s[n * 7 + p];
      }
    } else {
#pragma unroll
      for (int n = 0; n < 7; ++n)
#pragma unroll
        for (int p = 0; p < 7; ++p) P[n][p] = (n == p) ? 0.f : NEG2;
    }
    float* dstm = ((tid & 1) ? s1 : s0) + (tid >> 1) * MS;
#pragma unroll
    for (int n = 0; n < 7; ++n)
#pragma unroll
      for (int p = 0; p < 7; ++p) dstm[n * 8 + p] = P[n][p];
  } else {
    // ---- gold partial on waves 4-7, concurrent with pair phase ----
    const int t2 = tid - 256;
    float gp = 0.f;
    for (int t = t2; t < len; t += 256) {
      const int tag = tg[t];
      const int prev = t ? tg[t - 1] : START_;
      gp += ep[(size_t)t * 8 + tag] + tr2s[tag * 7 + prev];
    }
#pragma unroll
    for (int off = 32; off; off >>= 1) gp += __shfl_xor(gp, off, 64);
    if ((tid & 63) == 0) red[(tid >> 6) - 4] = gp;
  }
  __syncthreads();

  // ---- tree reduction: 256 -> 128 -> ... -> 1 ----
  level_fn<128>(s0, s1, MS, s0, tid);
  level_fn<64>(s0, s0 + MS, 2 * MS, s1, tid);
  level_fn<32>(s1, s1 + MS, 2 * MS, s0, tid);
  level_fn<16>(s0, s0 + MS, 2 * MS, s1, tid);
  level_fn<8>(s1, s1 + MS, 2 * MS, s0, tid);
  level_fn<4>(s0, s0 + MS, 2 * MS, s1, tid);
  level_fn<2>(s1, s1 + MS, 2 * MS, s0, tid);
  level_fn<1>(s0, s0 + MS, 2 * MS, s1, tid);     // final matrix in s1[0..]

  // ---- terminal + combine ----
  if (tid == 0) {
    float tt[7];
#pragma unroll
    for (int n = 0; n < 7; ++n) tt[n] = s1[n * 8 + START_] + tr2s[STOP_ * 7 + n];
    float mx = tt[0];
#pragma unroll
    for (int n = 1; n < 7; ++n) mx = fmaxf(mx, tt[n]);
    float s = 0.f;
#pragma unroll
    for (int n = 0; n < 7; ++n) s += fexp2(tt[n] - mx);
    const float fwd = mx + flog2(s);
    const float gold = red[0] + red[1] + red[2] + red[3] +
                       tr2s[STOP_ * 7 + tg[len - 1]];
    atomicAdd(out, (fwd - gold) * LN2);
  }
}

extern "C" void kernel_launch(void* const* d_in, const int* in_sizes, int n_in,
                              void* d_out, int out_size, void* d_ws, size_t ws_size,
                              hipStream_t stream) {
  const float* features    = (const float*)d_in[0];
  const int*   tags        = (const int*)d_in[1];
  const int*   lengths     = (const int*)d_in[2];
  const float* W           = (const float*)d_in[3];
  const float* bias        = (const float*)d_in[4];
  const float* transitions = (const float*)d_in[5];
  float* out = (float*)d_out;
  float* e2  = (float*)d_ws;  // [B*T][8] fp32 = 2 MB

  emis_kernel<<<2048, 256, 0, stream>>>(features, W, bias, e2, out);
  scan_kernel<<<B_, 512, 0, stream>>>(e2, tags, lengths, transitions, out);
}

// Round 6
// 59.958 us; speedup vs baseline: 3.2924x; 1.0528x over previous
//
#include <hip/hip_runtime.h>

#define B_ 128
#define T_ 512
#define H_ 1024
#define K_ 7
#define START_ 5
#define STOP_ 6
#define LOG2E 1.4426950408889634f
#define LN2 0.6931471805599453f
#define NEG2 (-10000.0f * 1.4426950408889634f)   // -10000 * log2(e)
#define MS 57   // LDS matrix stride in floats (odd -> conflict-spread)

typedef float f32x4 __attribute__((ext_vector_type(4)));

__device__ __forceinline__ float fexp2(float x) { return __builtin_amdgcn_exp2f(x); }
__device__ __forceinline__ float flog2(float x) { return __builtin_amdgcn_logf(x); }
__device__ __forceinline__ f32x4 ntload(const float* p) {
  return __builtin_nontemporal_load((const f32x4*)p);
}

// compute one row's 7 emissions from buffer R0..R3 and store to e2
#define COMPUTE_ROW(R0, R1, R2, R3, CUR)                                        \
  do {                                                                          \
    float acc[8];                                                               \
    _Pragma("unroll") for (int k = 0; k < 8; ++k) acc[k] = 0.0f;                \
    _Pragma("unroll") for (int k = 0; k < K_; ++k) {                            \
      acc[k] += R0.x * w[k][0].x + R0.y * w[k][0].y + R0.z * w[k][0].z + R0.w * w[k][0].w; \
      acc[k] += R1.x * w[k][1].x + R1.y * w[k][1].y + R1.z * w[k][1].z + R1.w * w[k][1].w; \
      acc[k] += R2.x * w[k][2].x + R2.y * w[k][2].y + R2.z * w[k][2].z + R2.w * w[k][2].w; \
      acc[k] += R3.x * w[k][3].x + R3.y * w[k][3].y + R3.z * w[k][3].z + R3.w * w[k][3].w; \
    }                                                                           \
    const bool b0 = lane & 1;                                                   \
    float k0 = b0 ? acc[4] : acc[0], s0 = b0 ? acc[0] : acc[4];                 \
    float k1 = b0 ? acc[5] : acc[1], s1 = b0 ? acc[1] : acc[5];                 \
    float k2 = b0 ? acc[6] : acc[2], s2 = b0 ? acc[2] : acc[6];                 \
    float k3 = b0 ? acc[7] : acc[3], s3 = b0 ? acc[3] : acc[7];                 \
    k0 += __shfl_xor(s0, 1, 64); k1 += __shfl_xor(s1, 1, 64);                   \
    k2 += __shfl_xor(s2, 1, 64); k3 += __shfl_xor(s3, 1, 64);                   \
    const bool b1 = lane & 2;                                                   \
    float m0 = b1 ? k2 : k0, t0 = b1 ? k0 : k2;                                 \
    float m1 = b1 ? k3 : k1, t1 = b1 ? k1 : k3;                                 \
    m0 += __shfl_xor(t0, 2, 64); m1 += __shfl_xor(t1, 2, 64);                   \
    const bool b2 = lane & 4;                                                   \
    float x = b2 ? m1 : m0, y = b2 ? m0 : m1;                                   \
    x += __shfl_xor(y, 4, 64);                                                  \
    x += __shfl_xor(x, 8, 64);                                                  \
    x += __shfl_xor(x, 16, 64);                                                 \
    x += __shfl_xor(x, 32, 64);                                                 \
    if (lane < 8 && vidx < K_)                                                  \
      e2[(size_t)(CUR) * 8 + vidx] = (x + myb) * LOG2E;                         \
  } while (0)

#define LOAD_ROW(R0, R1, R2, R3, J)                                             \
  do {                                                                          \
    const float* p_ = features + (size_t)(gwave + (J) * NW) * H_ + lane * 4;    \
    R0 = ntload(p_); R1 = ntload(p_ + 256);                                     \
    R2 = ntload(p_ + 512); R3 = ntload(p_ + 768);                               \
  } while (0)

// ---------------- Kernel 1: emissions (log2-scaled), W in registers ----------------
// Grid 512 x 256 = 2048 waves = exact residency at 2 waves/SIMD: ONE wave
// generation, W loaded once per wave, single 32-row self-timed pipeline.
// Triple-rotation depth-3 prefetch; body not unrolled across triples (I-cache).
__global__ __launch_bounds__(256, 2) void emis_kernel(
    const float* __restrict__ features, const float* __restrict__ W,
    const float* __restrict__ bias, float* __restrict__ e2, float* __restrict__ out) {
  if (blockIdx.x == 0 && threadIdx.x == 0) out[0] = 0.0f;  // zero scalar output

  const int tid = threadIdx.x;
  const int lane = tid & 63;
  const int gwave = blockIdx.x * 4 + (tid >> 6);   // 0..2047
  const int NW = 2048;

  // W fragment in registers: w[k][c] = W[k][c*256 + lane*4 .. +3]  (112 VGPRs)
  f32x4 w[K_][4];
#pragma unroll
  for (int k = 0; k < K_; ++k)
#pragma unroll
    for (int c = 0; c < 4; ++c)
      w[k][c] = *(const f32x4*)(W + k * H_ + c * 256 + lane * 4);

  // after the butterfly, lane l holds value index v = 4*bit0 | 2*bit1 | bit2
  const int vidx = ((lane & 1) << 2) | (lane & 2) | ((lane >> 2) & 1);
  float myb = 0.0f;
  if (vidx < K_) myb = bias[vidx];

  f32x4 A0, A1, A2, A3, B0, B1, B2, B3, C0, C1, C2, C3;
  LOAD_ROW(A0, A1, A2, A3, 0);
  LOAD_ROW(B0, B1, B2, B3, 1);
  LOAD_ROW(C0, C1, C2, C3, 2);

  // 9 triples: compute rows 0..26, prefetch rows 3..29 (all in-range)
  for (int jj = 0; jj < 9; ++jj) {
    const int j0 = 3 * jj;
    COMPUTE_ROW(A0, A1, A2, A3, gwave + j0 * NW);
    LOAD_ROW(A0, A1, A2, A3, j0 + 3);
    COMPUTE_ROW(B0, B1, B2, B3, gwave + (j0 + 1) * NW);
    LOAD_ROW(B0, B1, B2, B3, j0 + 4);
    COMPUTE_ROW(C0, C1, C2, C3, gwave + (j0 + 2) * NW);
    LOAD_ROW(C0, C1, C2, C3, j0 + 5);
  }
  // tail: rows 27..31 (prefetch 30,31 during 27,28)
  COMPUTE_ROW(A0, A1, A2, A3, gwave + 27 * NW);
  LOAD_ROW(A0, A1, A2, A3, 30);
  COMPUTE_ROW(B0, B1, B2, B3, gwave + 28 * NW);
  LOAD_ROW(B0, B1, B2, B3, 31);
  COMPUTE_ROW(C0, C1, C2, C3, gwave + 29 * NW);
  COMPUTE_ROW(A0, A1, A2, A3, gwave + 30 * NW);
  COMPUTE_ROW(B0, B1, B2, B3, gwave + 31 * NW);
}

// ---------------- tree-compose level: NM outputs from 2*NM inputs, 512 threads ----------------
template <int NM>
__device__ __forceinline__ void level_fn(const float* __restrict__ evenB,
                                         const float* __restrict__ oddB,
                                         int qstride, float* __restrict__ dst,
                                         int tid) {
  constexpr int TOT = NM * 49;
  constexpr int NI = (TOT + 511) / 512;
  float tmp[NI];
#pragma unroll
  for (int i = 0; i < NI; ++i) {
    const int u = tid + i * 512;
    if (u < TOT) {
      const int q = u / 49, r = u - 49 * q, n = r / 7, p = r - 7 * n;
      const float* hi = oddB + q * qstride;
      const float* lo = evenB + q * qstride;
      float qq[7];
#pragma unroll
      for (int m = 0; m < 7; ++m) qq[m] = hi[n * 8 + m] + lo[m * 8 + p];
      float mx = fmaxf(fmaxf(fmaxf(qq[0], qq[1]), fmaxf(qq[2], qq[3])),
                       fmaxf(fmaxf(qq[4], qq[5]), qq[6]));
      float s = 0.f;
#pragma unroll
      for (int m = 0; m < 7; ++m) s += fexp2(qq[m] - mx);
      tmp[i] = mx + flog2(s);
    }
  }
  __syncthreads();
#pragma unroll
  for (int i = 0; i < NI; ++i) {
    const int u = tid + i * 512;
    if (u < TOT) {
      const int q = u / 49, r = u - 49 * q, n = r / 7, p = r - 7 * n;
      dst[q * MS + n * 8 + p] = tmp[i];
    }
  }
  __syncthreads();
}

// ---------------- Kernel 2: per-batch tree scan + gold, 512 threads ----------------
// Waves 0-3: pair phase (no-max lse; emissions are N(0,1)-scale, |q| <~ 25).
// Waves 4-7: gold score, concurrent. Then all 8 waves run the tree levels.
__global__ __launch_bounds__(512) void scan_kernel(
    const float* __restrict__ e2, const int* __restrict__ tags,
    const int* __restrict__ lengths, const float* __restrict__ transitions,
    float* __restrict__ out) {
  __shared__ float s0[128 * MS];   // 29184 B
  __shared__ float s1[128 * MS];   // 29184 B
  __shared__ float tr2s[49];
  __shared__ float red[4];

  const int tid = threadIdx.x;
  const int b = blockIdx.x;
  const int len = lengths[b];

  if (tid < 49) tr2s[tid] = transitions[tid] * LOG2E;
  __syncthreads();

  const int* tg = tags + (size_t)b * T_;
  const float* ep = e2 + (size_t)b * T_ * 8;

  if (tid < 256) {
    // ---- pair phase: thread tid builds pair-matrix for steps (2*tid, 2*tid+1) ----
    const int t0 = 2 * tid, t1 = 2 * tid + 1;
    float P[7][7];
    if (t1 < len) {
      const f32x4* ev = (const f32x4*)(ep + (size_t)t0 * 8);  // 64B: e0[0..7], e1[0..7]
      const f32x4 ca = ev[0], cb = ev[1], da = ev[2], db = ev[3];
      const float c[7]  = {ca.x, ca.y, ca.z, ca.w, cb.x, cb.y, cb.z};
      const float e1[7] = {da.x, da.y, da.z, da.w, db.x, db.y, db.z};
#pragma unroll
      for (int n = 0; n < 7; ++n) {
        float a[7];
#pragma unroll
        for (int m = 0; m < 7; ++m) a[m] = tr2s[n * 7 + m] + c[m];
#pragma unroll
        for (int p = 0; p < 7; ++p) {
          // no-max logsumexp: NEG entries underflow to 0; +1e-37 keeps
          // all-underflow rows finite (~-123 soft sentinel, still << real vals)
          float s = 1e-37f;
#pragma unroll
          for (int m = 0; m < 7; ++m) s += fexp2(a[m] + tr2s[m * 7 + p]);
          P[n][p] = e1[n] + flog2(s);
        }
      }
    } else if (t0 < len) {
      const f32x4* ev = (const f32x4*)(ep + (size_t)t0 * 8);
      const f32x4 ca = ev[0], cb = ev[1];
      const float c[7] = {ca.x, ca.y, ca.z, ca.w, cb.x, cb.y, cb.z};
#pragma unroll
      for (int n = 0; n < 7; ++n) {
#pragma unroll
        for (int p = 0; p < 7; ++p) P[n][p] = c[n] + tr2s[n * 7 + p];
      }
    } else {
#pragma unroll
      for (int n = 0; n < 7; ++n)
#pragma unroll
        for (int p = 0; p < 7; ++p) P[n][p] = (n == p) ? 0.f : NEG2;
    }
    float* dstm = ((tid & 1) ? s1 : s0) + (tid >> 1) * MS;
#pragma unroll
    for (int n = 0; n < 7; ++n)
#pragma unroll
      for (int p = 0; p < 7; ++p) dstm[n * 8 + p] = P[n][p];
  } else {
    // ---- gold partial on waves 4-7, concurrent with pair phase ----
    const int t2 = tid - 256;
    float gp = 0.f;
    for (int t = t2; t < len; t += 256) {
      const int tag = tg[t];
      const int prev = t ? tg[t - 1] : START_;
      gp += ep[(size_t)t * 8 + tag] + tr2s[tag * 7 + prev];
    }
#pragma unroll
    for (int off = 32; off; off >>= 1) gp += __shfl_xor(gp, off, 64);
    if ((tid & 63) == 0) red[(tid >> 6) - 4] = gp;
  }
  __syncthreads();

  // ---- tree reduction: 256 -> 128 -> ... -> 1 ----
  level_fn<128>(s0, s1, MS, s0, tid);
  level_fn<64>(s0, s0 + MS, 2 * MS, s1, tid);
  level_fn<32>(s1, s1 + MS, 2 * MS, s0, tid);
  level_fn<16>(s0, s0 + MS, 2 * MS, s1, tid);
  level_fn<8>(s1, s1 + MS, 2 * MS, s0, tid);
  level_fn<4>(s0, s0 + MS, 2 * MS, s1, tid);
  level_fn<2>(s1, s1 + MS, 2 * MS, s0, tid);
  level_fn<1>(s0, s0 + MS, 2 * MS, s1, tid);     // final matrix in s1[0..]

  // ---- terminal + combine ----
  if (tid == 0) {
    float tt[7];
#pragma unroll
    for (int n = 0; n < 7; ++n) tt[n] = s1[n * 8 + START_] + tr2s[STOP_ * 7 + n];
    float mx = tt[0];
#pragma unroll
    for (int n = 1; n < 7; ++n) mx = fmaxf(mx, tt[n]);
    float s = 0.f;
#pragma unroll
    for (int n = 0; n < 7; ++n) s += fexp2(tt[n] - mx);
    const float fwd = mx + flog2(s);
    const float gold = red[0] + red[1] + red[2] + red[3] +
                       tr2s[STOP_ * 7 + tg[len - 1]];
    atomicAdd(out, (fwd - gold) * LN2);
  }
}

extern "C" void kernel_launch(void* const* d_in, const int* in_sizes, int n_in,
                              void* d_out, int out_size, void* d_ws, size_t ws_size,
                              hipStream_t stream) {
  const float* features    = (const float*)d_in[0];
  const int*   tags        = (const int*)d_in[1];
  const int*   lengths     = (const int*)d_in[2];
  const float* W           = (const float*)d_in[3];
  const float* bias        = (const float*)d_in[4];
  const float* transitions = (const float*)d_in[5];
  float* out = (float*)d_out;
  float* e2  = (float*)d_ws;  // [B*T][8] fp32 = 2 MB

  emis_kernel<<<512, 256, 0, stream>>>(features, W, bias, e2, out);
  scan_kernel<<<B_, 512, 0, stream>>>(e2, tags, lengths, transitions, out);
}